// Round 7
// baseline (316.245 us; speedup 1.0000x reference)
//
#include <hip/hip_runtime.h>

typedef __attribute__((ext_vector_type(8))) short bf16x8;
typedef __attribute__((ext_vector_type(8))) _Float16 f16x8;
typedef __attribute__((ext_vector_type(2))) __fp16 fp16v2;
typedef __attribute__((ext_vector_type(4))) float f32x4;

#define DDIM 128
#define NADDR 4096
#define VDIM 512
#define NT 32
#define NITER (NADDR/NT)
#define LOG2E 1.44269504088896340736f

// pack hi16(lo)->low short, hi16(hi)->high short (bf16 truncation)
__device__ __forceinline__ unsigned pkhi(float hi, float lo){
  return __builtin_amdgcn_perm(__float_as_uint(hi), __float_as_uint(lo), 0x07060302u);
}

__global__ __launch_bounds__(512, 4)
void soft_addr_kernel(const float* __restrict__ sel,
                      const float* __restrict__ bank,
                      const float* __restrict__ addr,
                      float* __restrict__ out)
{
  // Double-buffered, XOR-swizzled tiles (width-32 rows for sVt/sP):
  //  sK : [n=32][d=128] fp16, 16B-group g' = g ^ (n&7)        (16 groups/row)
  //  sVt: [v=128][n=32] bf16, group g' = g ^ ((v>>1)&3)       (4 groups/row)
  //  sP : [m=128][n=32] bf16, group g' = g ^ ((m>>1)&3)
  __shared__ __align__(16) _Float16 sK[2][32*128];
  __shared__ __align__(16) short   sVt[2][128*32];
  __shared__ __align__(16) short    sP[2][128*32];
  __shared__ float sL[2][128];

  const int tid  = threadIdx.x;
  const int wave = tid >> 6;
  const int lane = tid & 63;
  const int quad = lane >> 4;
  const int l16  = lane & 15;

  const int bid  = blockIdx.x;
  const int vblk = bid & 3;
  const int mblk = bid >> 2;
  const int m0 = mblk*128, v0 = vblk*128;

  const int mb   = wave >> 1;        // m-band 0..3
  const int half = wave & 1;
  const int swr  = 32*mb;            // row band (32 rows)
  const int sc16 = 16*half;          // S col base (16 of 32)
  const int wn   = 64*half;          // PV col base (64 of 128)

  // ---- Q fragments (A layout), pre-scaled by log2(e), fp16, loop-invariant ----
  f16x8 aQ[2][4];
  #pragma unroll
  for (int mi = 0; mi < 2; ++mi){
    const float* q = sel + (size_t)(m0 + swr + 16*mi + l16) * DDIM + quad*8;
    #pragma unroll
    for (int ks = 0; ks < 4; ++ks){
      float4 a = *(const float4*)(q + 32*ks);
      float4 b = *(const float4*)(q + 32*ks + 4);
      f16x8 f;
      f[0]=(_Float16)(a.x*LOG2E); f[1]=(_Float16)(a.y*LOG2E);
      f[2]=(_Float16)(a.z*LOG2E); f[3]=(_Float16)(a.w*LOG2E);
      f[4]=(_Float16)(b.x*LOG2E); f[5]=(_Float16)(b.y*LOG2E);
      f[6]=(_Float16)(b.z*LOG2E); f[7]=(_Float16)(b.w*LOG2E);
      aQ[mi][ks] = f;
    }
  }

  f32x4 oAcc[2][4];
  const f32x4 fz = {0.f,0.f,0.f,0.f};
  #pragma unroll
  for (int i=0;i<2;++i)
    #pragma unroll
    for (int j=0;j<4;++j) oAcc[i][j]=fz;
  float lacc[2][4] = {{0.f,0.f,0.f,0.f},{0.f,0.f,0.f,0.f}};

  // staging maps
  const int ksr = tid >> 4;                 // K row 0..31
  const int kj  = tid & 15;                 // K 16B-group 0..15
  const int ksw = ksr*128 + (((kj ^ (ksr&7)) & 15) << 3);
  const float* kbase = addr + (size_t)ksr*DDIM + 8*kj;

  const int vc  = tid & 127;                // V column 0..127
  const int vt  = tid >> 7;                 // n-group 0..3
  const int vsw = vc*32 + (((vt ^ ((vc>>1)&3)) & 3) << 3);
  const float* vbase = bank + (size_t)(8*vt)*VDIM + v0 + vc;

  // frag addresses (swizzled element offsets), loop-invariant
  const int rK   = sc16 + l16;              // bK row
  int bkOff[4];
  #pragma unroll
  for (int ks=0; ks<4; ++ks)
    bkOff[ks] = rK*128 + ((((4*ks + quad) ^ (rK&7)) & 15) << 3);
  int apOff[2];
  #pragma unroll
  for (int mi=0; mi<2; ++mi){
    const int m = swr + 16*mi + l16;
    apOff[mi] = m*32 + (((quad ^ ((m>>1)&3)) & 3) << 3);
  }
  int bvOff[4];
  #pragma unroll
  for (int jx=0; jx<4; ++jx){
    const int v = wn + 16*jx + l16;
    bvOff[jx] = v*32 + (((quad ^ ((v>>1)&3)) & 3) << 3);
  }

  // ---- stage tile 0 ----
  {
    const float* ksrc = kbase;
    float4 a = *(const float4*)(ksrc);
    float4 b = *(const float4*)(ksrc+4);
    union { f16x8 v; fp16v2 h[4]; } u;
    u.h[0] = __builtin_amdgcn_cvt_pkrtz(a.x, a.y);
    u.h[1] = __builtin_amdgcn_cvt_pkrtz(a.z, a.w);
    u.h[2] = __builtin_amdgcn_cvt_pkrtz(b.x, b.y);
    u.h[3] = __builtin_amdgcn_cvt_pkrtz(b.z, b.w);
    *(f16x8*)&sK[0][ksw] = u.v;
    const float* vsrc = vbase;
    float v[8];
    #pragma unroll
    for (int j=0;j<8;++j) v[j] = vsrc[(size_t)j*VDIM];
    uint4 pk;
    pk.x = pkhi(v[1], v[0]); pk.y = pkhi(v[3], v[2]);
    pk.z = pkhi(v[5], v[4]); pk.w = pkhi(v[7], v[6]);
    *(uint4*)&sVt[0][vsw] = pk;
  }

  for (int nt = 0; nt < NITER; ++nt){
    const int p = nt & 1;
    __syncthreads();   // A: stage(nt) visible; prev compute reads of buf p done

    // ---- S(nt): 32 rows x 16 cols, K=128 (fp16) ----
    f32x4 sAcc[2];
    sAcc[0]=fz; sAcc[1]=fz;
    #pragma unroll
    for (int ks=0; ks<4; ++ks){
      f16x8 bK = *(const f16x8*)&sK[p][bkOff[ks]];
      sAcc[0] = __builtin_amdgcn_mfma_f32_16x16x32_f16(aQ[0][ks], bK, sAcc[0], 0,0,0);
      sAcc[1] = __builtin_amdgcn_mfma_f32_16x16x32_f16(aQ[1][ks], bK, sAcc[1], 0,0,0);
    }

    // ---- PV(nt-1): 32 rows x 64 cols, K=32 (bf16) -- independent of S(nt) ----
    if (nt > 0){
      const int q = 1 - p;
      bf16x8 aP0 = *(const bf16x8*)&sP[q][apOff[0]];
      bf16x8 aP1 = *(const bf16x8*)&sP[q][apOff[1]];
      #pragma unroll
      for (int jx=0; jx<4; ++jx){
        bf16x8 bV = *(const bf16x8*)&sVt[q][bvOff[jx]];
        oAcc[0][jx] = __builtin_amdgcn_mfma_f32_16x16x32_bf16(aP0, bV, oAcc[0][jx], 0,0,0);
        oAcc[1][jx] = __builtin_amdgcn_mfma_f32_16x16x32_bf16(aP1, bV, oAcc[1][jx], 0,0,0);
      }
    }

    // ---- P = 2^S, truncate bf16, pair via DPP, b32 write into sP[p] ----
    #pragma unroll
    for (int mi=0; mi<2; ++mi)
      #pragma unroll
      for (int r=0; r<4; ++r){
        float pe = __builtin_amdgcn_exp2f(sAcc[mi][r]);
        unsigned pu = __float_as_uint(pe);
        lacc[mi][r] += __uint_as_float(pu & 0xffff0000u);
        unsigned pou = (unsigned)__builtin_amdgcn_mov_dpp((int)pu, 0xB1, 0xF, 0xF, true);
        if (!(l16 & 1)){
          const int m = swr + 16*mi + 4*quad + r;
          const int c = sc16 + l16;
          *(unsigned*)&sP[p][m*32 + ((((c>>3) ^ ((m>>1)&3)) & 3) << 3) + (c&7)] =
              __builtin_amdgcn_perm(pou, pu, 0x07060302u);
        }
      }

    __syncthreads();   // B: all compute reads of buf (1-p) done

    // ---- stage(nt+1) into buf (1-p) ----
    if (nt + 1 < NITER){
      const int n0 = (nt + 1) * NT;
      const float* ksrc = kbase + (size_t)n0*DDIM;
      float4 a = *(const float4*)(ksrc);
      float4 b = *(const float4*)(ksrc+4);
      union { f16x8 v; fp16v2 h[4]; } u;
      u.h[0] = __builtin_amdgcn_cvt_pkrtz(a.x, a.y);
      u.h[1] = __builtin_amdgcn_cvt_pkrtz(a.z, a.w);
      u.h[2] = __builtin_amdgcn_cvt_pkrtz(b.x, b.y);
      u.h[3] = __builtin_amdgcn_cvt_pkrtz(b.z, b.w);
      *(f16x8*)&sK[1-p][ksw] = u.v;
      const float* vsrc = vbase + (size_t)n0*VDIM;
      float v[8];
      #pragma unroll
      for (int j=0;j<8;++j) v[j] = vsrc[(size_t)j*VDIM];
      uint4 pk;
      pk.x = pkhi(v[1], v[0]); pk.y = pkhi(v[3], v[2]);
      pk.z = pkhi(v[5], v[4]); pk.w = pkhi(v[7], v[6]);
      *(uint4*)&sVt[1-p][vsw] = pk;
    }
  }

  // ---- drain: PV(NITER-1) from buf (NITER-1)&1 = 1 ----
  {
    bf16x8 aP0 = *(const bf16x8*)&sP[1][apOff[0]];
    bf16x8 aP1 = *(const bf16x8*)&sP[1][apOff[1]];
    #pragma unroll
    for (int jx=0; jx<4; ++jx){
      bf16x8 bV = *(const bf16x8*)&sVt[1][bvOff[jx]];
      oAcc[0][jx] = __builtin_amdgcn_mfma_f32_16x16x32_bf16(aP0, bV, oAcc[0][jx], 0,0,0);
      oAcc[1][jx] = __builtin_amdgcn_mfma_f32_16x16x32_bf16(aP1, bV, oAcc[1][jx], 0,0,0);
    }
  }

  // ---- partial denominators (wave covered 16 of 32 cols per n-tile) ----
  #pragma unroll
  for (int mi=0; mi<2; ++mi)
    #pragma unroll
    for (int r=0;r<4;++r){
      float s = lacc[mi][r];
      s += __shfl_xor(s, 1);
      s += __shfl_xor(s, 2);
      s += __shfl_xor(s, 4);
      s += __shfl_xor(s, 8);
      if (l16 == 0) sL[half][swr + 16*mi + 4*quad + r] = s;
    }
  __syncthreads();

  // ---- epilogue: divide + store ----
  #pragma unroll
  for (int i=0;i<2;++i){
    #pragma unroll
    for (int r=0;r<4;++r){
      int row = swr + 16*i + 4*quad + r;
      float inv = 1.0f / (sL[0][row] + sL[1][row]);
      float* op = out + (size_t)(m0 + row)*VDIM + v0 + wn;
      #pragma unroll
      for (int jx=0;jx<4;++jx)
        op[16*jx + l16] = oAcc[i][jx][r] * inv;
    }
  }
}

extern "C" void kernel_launch(void* const* d_in, const int* in_sizes, int n_in,
                              void* d_out, int out_size, void* d_ws, size_t ws_size,
                              hipStream_t stream) {
  const float* sel  = (const float*)d_in[0];   // [8,2048,128]
  const float* bank = (const float*)d_in[1];   // [4096,512]
  const float* addr = (const float*)d_in[2];   // [4096,128]
  float* out = (float*)d_out;                  // [8,2048,512]
  dim3 grid(512), block(512);
  hipLaunchKernelGGL(soft_addr_kernel, grid, block, 0, stream, sel, bank, addr, out);
}